// Round 4
// baseline (279.802 us; speedup 1.0000x reference)
//
#include <hip/hip_runtime.h>
#include <hip/hip_bf16.h>
#include <stdint.h>

// Shapes: B=2, N=2048, D=2048, H=16, Dh=128, M=B*N=4096
// Workspace layout (bytes):
//   xb   @ 0          bf16 x (4096x2048)
//   wqT  @ 16777216   bf16 Wq^T (2048,2048)   } contiguous => W_qkv^T (6144,2048)
//   wkT  @ 25165824
//   wvT  @ 33554432
//   woT  @ 41943040
//   qb   @ 50331648   bf16 Q (B,H,N,Dh)  (rope+scale applied)
//   kb   @ 67108864   bf16 K (B,H,N,Dh)  (rope applied)
//   vt   @ 83886080   bf16 V^T (B,H,Dh,N)
//   ab   @ 100663296  bf16 attn_out (B,N,D)

typedef __attribute__((ext_vector_type(4))) float f32x4;
typedef __attribute__((ext_vector_type(8))) short bf16x8;

__device__ __forceinline__ unsigned short f2bf(float f){
  unsigned u = __builtin_bit_cast(unsigned, f);
  u += 0x7FFFu + ((u >> 16) & 1u);
  return (unsigned short)(u >> 16);
}
__device__ __forceinline__ float bf2f(unsigned short h){
  unsigned u = ((unsigned)h) << 16;
  return __builtin_bit_cast(float, u);
}
__device__ __forceinline__ void gload16(const void* g, void* l){
  __builtin_amdgcn_global_load_lds((const __attribute__((address_space(1))) void*)g,
                                   (__attribute__((address_space(3))) void*)l, 16, 0, 0);
}

// ---------------- elementwise f32 -> bf16 ----------------
__global__ void k_cvt(const float* __restrict__ src, unsigned short* __restrict__ dst, int n4){
  int i = blockIdx.x * 256 + threadIdx.x;
  if (i >= n4) return;
  float4 v = ((const float4*)src)[i];
  unsigned long long pk = (unsigned long long)f2bf(v.x)
    | ((unsigned long long)f2bf(v.y) << 16)
    | ((unsigned long long)f2bf(v.z) << 32)
    | ((unsigned long long)f2bf(v.w) << 48);
  ((unsigned long long*)dst)[i] = pk;
}

// ---------------- all four W (K,N) f32 -> W^T (N,K) bf16, one launch ----------------
__global__ void k_transpose_all(const float* __restrict__ W0, const float* __restrict__ W1,
                                const float* __restrict__ W2, const float* __restrict__ W3,
                                unsigned short* __restrict__ WT){
  const float* W = (blockIdx.z == 0) ? W0 : (blockIdx.z == 1) ? W1 : (blockIdx.z == 2) ? W2 : W3;
  unsigned short* dst = WT + (size_t)blockIdx.z * 4194304;
  __shared__ float tile[64][65];
  int t = threadIdx.x;
  int cc = t & 63, rb = t >> 6;
  int bx = blockIdx.x * 64;   // n base
  int by = blockIdx.y * 64;   // k base
  #pragma unroll
  for (int i = 0; i < 16; i++){
    int r = rb + i * 4;
    tile[r][cc] = W[(size_t)(by + r) * 2048 + bx + cc];
  }
  __syncthreads();
  #pragma unroll
  for (int i = 0; i < 16; i++){
    int r = rb + i * 4;
    dst[(size_t)(bx + r) * 2048 + by + cc] = f2bf(tile[cc][r]);
  }
}

// ---------------- fused QKV GEMM + RoPE epilogue ----------------
// XCD swizzle: each XCD owns a 6-column n-tile band -> its W^T working set
// (6*128 rows * 4KB = 3MB) fits the 4MB per-XCD L2.
__global__ __launch_bounds__(256, 3) void k_gemm_qkv(
    const unsigned short* __restrict__ A,
    const unsigned short* __restrict__ Bt,
    unsigned short* __restrict__ Oq,
    unsigned short* __restrict__ Ok,
    unsigned short* __restrict__ Ov,
    const float* __restrict__ ropeq,
    const float* __restrict__ ropek)
{
  const int Kdim = 2048;
  __shared__ unsigned short As[128 * 64];
  __shared__ unsigned short Bs[128 * 64];
  const int tid = threadIdx.x;
  const int w = tid >> 6, l = tid & 63, g = l >> 4, c = l & 15;
  // 1536 blocks: i%8 = XCD; XCD j gets n-tiles [6j, 6j+6), all 32 m-tiles
  const int i0 = blockIdx.y * 32 + blockIdx.x;
  const int xcd = i0 & 7, kb2 = i0 >> 3;
  const int bm = (kb2 & 31) * 128;
  const int bn = (xcd * 6 + (kb2 >> 5)) * 128;
  const int mw = (w >> 1) * 64, nw = (w & 1) * 64;
  f32x4 acc[4][4] = {};
  const int srow = l >> 3;
  const int sbyte = (((l & 7) ^ srow) << 4);
  const char* Ab = (const char*)A;
  const char* Bb = (const char*)Bt;
  char* AsB = (char*)As; char* BsB = (char*)Bs;

  for (int kt = 0; kt < Kdim; kt += 64){
    __syncthreads();
    #pragma unroll
    for (int j = 0; j < 4; j++){
      int chunk = w * 4 + j;
      int row = chunk * 8 + srow;
      gload16(Ab + ((size_t)(bm + row) * Kdim + kt) * 2 + sbyte, AsB + chunk * 1024);
      gload16(Bb + ((size_t)(bn + row) * Kdim + kt) * 2 + sbyte, BsB + chunk * 1024);
    }
    __syncthreads();
    #pragma unroll
    for (int kk = 0; kk < 2; kk++){
      bf16x8 av[4], bv[4];
      #pragma unroll
      for (int i = 0; i < 4; i++){
        int m = mw + i * 16 + c;
        av[i] = *(const bf16x8*)(AsB + m * 128 + ((kk * 64 + g * 16) ^ ((m & 7) << 4)));
        int n = nw + i * 16 + c;
        bv[i] = *(const bf16x8*)(BsB + n * 128 + ((kk * 64 + g * 16) ^ ((n & 7) << 4)));
      }
      #pragma unroll
      for (int i = 0; i < 4; i++)
        #pragma unroll
        for (int jj = 0; jj < 4; jj++)
          acc[i][jj] = __builtin_amdgcn_mfma_f32_16x16x32_bf16(av[i], bv[jj], acc[i][jj], 0, 0, 0);
    }
  }

  const int matsel = bn >> 11;        // 0=Q 1=K 2=V
  const int hh = (bn >> 7) & 15;      // head
  if (matsel < 2){
    unsigned short* O = matsel ? Ok : Oq;
    const float* rope = matsel ? ropek : ropeq;
    const float scale = matsel ? 1.0f : (1.0f / 128.0f);
    #pragma unroll
    for (int i = 0; i < 4; i++){
      int m0 = bm + mw + i * 16 + g * 4;
      #pragma unroll
      for (int jj = 0; jj < 4; jj++){
        int d = nw + jj * 16 + c;   // 0..127 within head
        int dbase = d & ~1;
        int odd = d & 1;
        #pragma unroll
        for (int r = 0; r < 4; r++){
          int m = m0 + r;
          int b = m >> 11, tok = m & 2047;
          float v = acc[i][jj][r];
          float vp = __shfl_xor(v, 1);
          float2 rv = *(const float2*)(rope + (((size_t)(b * 2048 + tok)) << 7) + dbase);
          float xr = odd ? vp : v;
          float xi = odd ? v : vp;
          float res = odd ? (xr * rv.y + xi * rv.x) : (xr * rv.x - xi * rv.y);
          O[(((size_t)(b * 16 + hh) * 2048 + tok) << 7) + d] = f2bf(res * scale);
        }
      }
    }
  } else { // V -> (B,H,Dh,N)
    #pragma unroll
    for (int i = 0; i < 4; i++){
      int m0 = bm + mw + i * 16 + g * 4;
      int b = m0 >> 11, tok0 = m0 & 2047;
      #pragma unroll
      for (int jj = 0; jj < 4; jj++){
        int d = nw + jj * 16 + c;
        unsigned long long pk = (unsigned long long)f2bf(acc[i][jj][0])
          | ((unsigned long long)f2bf(acc[i][jj][1]) << 16)
          | ((unsigned long long)f2bf(acc[i][jj][2]) << 32)
          | ((unsigned long long)f2bf(acc[i][jj][3]) << 48);
        *(unsigned long long*)(Ov + ((size_t)(b * 16 + hh) * 128 + d) * 2048 + tok0) = pk;
      }
    }
  }
}

// ---------------- output GEMM: d_out = ab @ Wo + bo (f32 out) ----------------
__global__ __launch_bounds__(256, 3) void k_gemm_out(
    const unsigned short* __restrict__ A,
    const unsigned short* __restrict__ Bt,
    float* __restrict__ O,
    const float* __restrict__ bias)
{
  const int Kdim = 2048;
  __shared__ unsigned short As[128 * 64];
  __shared__ unsigned short Bs[128 * 64];
  const int tid = threadIdx.x;
  const int w = tid >> 6, l = tid & 63, g = l >> 4, c = l & 15;
  // 512 blocks: XCD j gets n-tiles [2j, 2j+2), all 32 m-tiles
  const int i0 = blockIdx.y * 32 + blockIdx.x;
  const int xcd = i0 & 7, kb2 = i0 >> 3;
  const int bm = (kb2 & 31) * 128;
  const int bn = (xcd * 2 + (kb2 >> 5)) * 128;
  const int mw = (w >> 1) * 64, nw = (w & 1) * 64;
  f32x4 acc[4][4] = {};
  const int srow = l >> 3;
  const int sbyte = (((l & 7) ^ srow) << 4);
  const char* Ab = (const char*)A;
  const char* Bb = (const char*)Bt;
  char* AsB = (char*)As; char* BsB = (char*)Bs;

  for (int kt = 0; kt < Kdim; kt += 64){
    __syncthreads();
    #pragma unroll
    for (int j = 0; j < 4; j++){
      int chunk = w * 4 + j;
      int row = chunk * 8 + srow;
      gload16(Ab + ((size_t)(bm + row) * Kdim + kt) * 2 + sbyte, AsB + chunk * 1024);
      gload16(Bb + ((size_t)(bn + row) * Kdim + kt) * 2 + sbyte, BsB + chunk * 1024);
    }
    __syncthreads();
    #pragma unroll
    for (int kk = 0; kk < 2; kk++){
      bf16x8 av[4], bv[4];
      #pragma unroll
      for (int i = 0; i < 4; i++){
        int m = mw + i * 16 + c;
        av[i] = *(const bf16x8*)(AsB + m * 128 + ((kk * 64 + g * 16) ^ ((m & 7) << 4)));
        int n = nw + i * 16 + c;
        bv[i] = *(const bf16x8*)(BsB + n * 128 + ((kk * 64 + g * 16) ^ ((n & 7) << 4)));
      }
      #pragma unroll
      for (int i = 0; i < 4; i++)
        #pragma unroll
        for (int jj = 0; jj < 4; jj++)
          acc[i][jj] = __builtin_amdgcn_mfma_f32_16x16x32_bf16(av[i], bv[jj], acc[i][jj], 0, 0, 0);
    }
  }
  #pragma unroll
  for (int i = 0; i < 4; i++){
    int m0 = bm + mw + i * 16 + g * 4;
    #pragma unroll
    for (int jj = 0; jj < 4; jj++){
      int n = bn + nw + jj * 16 + c;
      float bv2 = bias[n];
      #pragma unroll
      for (int r = 0; r < 4; r++)
        O[(size_t)(m0 + r) * 2048 + n] = acc[i][jj][r] + bv2;
    }
  }
}

// ---------------- Flash attention ----------------
// Q in regs, K/V double-buffered, fixed-base softmax (|S|<~1 here), deferred
// l-reduction, conflict-free P swizzle, XCD swizzle (4 heads' K+V = 4MB / L2).
__global__ __launch_bounds__(256, 2) void k_attn(
    const unsigned short* __restrict__ Q,
    const unsigned short* __restrict__ Kg,
    const unsigned short* __restrict__ VT,
    unsigned short* __restrict__ Ao)
{
  __shared__ char sh[81920];
  // layout: K0 @0 (16KB) | K1 @16KB | V0 @32KB | V1 @48KB | Ps @64KB (16KB)
  char* PsB = sh + 65536;
  const int tid = threadIdx.x;
  const int w = tid >> 6, l = tid & 63, g = l >> 4, c = l & 15;
  // 512 blocks: XCD j gets heads [4j, 4j+4), all 16 q-tiles
  const int i0 = blockIdx.y * 16 + blockIdx.x;
  const int xcd = i0 & 7, kb2 = i0 >> 3;
  const int bh = xcd * 4 + (kb2 >> 4);
  const int qt = kb2 & 15;
  const char* Qb = (const char*)(Q + (((size_t)bh * 2048 + qt * 128) << 7));
  const char* Kb = (const char*)(Kg + ((size_t)bh << 18));
  const char* Vb = (const char*)(VT + ((size_t)bh << 18));
  const int rsub = l >> 4;
  const int byte0 = (l & 15) << 4;
  const int drow = l >> 3;
  const int vbyte = (((l & 7) ^ drow) << 4);

  // stage Q tile (32KB) through K0|K1 region, then hoist frags to regs
  #pragma unroll
  for (int j = 0; j < 8; j++){
    int chunk = w * 8 + j;
    int row = chunk * 4 + rsub;
    gload16(Qb + (size_t)row * 256 + (byte0 ^ ((row & 7) << 4)), sh + chunk * 1024);
  }
  __syncthreads();
  bf16x8 qa[4][2];
  #pragma unroll
  for (int kk = 0; kk < 4; kk++)
    #pragma unroll
    for (int mf = 0; mf < 2; mf++){
      int q = w * 32 + mf * 16 + c;
      qa[kk][mf] = *(const bf16x8*)(sh + q * 256 + ((kk * 64 + g * 16) ^ ((q & 7) << 4)));
    }
  __syncthreads();   // frag reads done before staging overwrites

  auto stageKV = [&](int kv, int buf){
    char* Kc = sh + buf * 16384;
    char* Vc = sh + 32768 + buf * 16384;
    #pragma unroll
    for (int j = 0; j < 4; j++){
      int chunk = w * 4 + j;
      int row = chunk * 4 + rsub;
      gload16(Kb + (size_t)(kv * 64 + row) * 256 + (byte0 ^ ((row & 7) << 4)), Kc + chunk * 1024);
    }
    #pragma unroll
    for (int j = 0; j < 4; j++){
      int chunk = w * 4 + j;
      int d = chunk * 8 + drow;
      gload16(Vb + (size_t)d * 4096 + kv * 128 + vbyte, Vc + chunk * 1024);
    }
  };

  f32x4 oacc[2][8] = {};
  float lpart[2][4] = {};

  stageKV(0, 0);
  __syncthreads();

  for (int kv = 0; kv < 32; kv++){
    int cur = kv & 1;
    if (kv < 31) stageKV(kv + 1, cur ^ 1);   // flies under QK^T + exp
    char* Kc = sh + cur * 16384;
    char* Vc = sh + 32768 + cur * 16384;

    // S = Q K^T  (wave: 32 q-rows x 64 keys)
    f32x4 sacc[2][4] = {};
    __builtin_amdgcn_s_setprio(1);
    #pragma unroll
    for (int kk = 0; kk < 4; kk++){
      bf16x8 kbf[4];
      #pragma unroll
      for (int nf = 0; nf < 4; nf++){
        int kx = nf * 16 + c;
        kbf[nf] = *(const bf16x8*)(Kc + kx * 256 + ((kk * 64 + g * 16) ^ ((kx & 7) << 4)));
      }
      #pragma unroll
      for (int mf = 0; mf < 2; mf++)
        #pragma unroll
        for (int nf = 0; nf < 4; nf++)
          sacc[mf][nf] = __builtin_amdgcn_mfma_f32_16x16x32_bf16(qa[kk][mf], kbf[nf], sacc[mf][nf], 0, 0, 0);
    }
    __builtin_amdgcn_s_setprio(0);

    // fixed-base softmax numerator: P = exp(S), per-lane partial row sums.
    #pragma unroll
    for (int mf = 0; mf < 2; mf++)
      #pragma unroll
      for (int nf = 0; nf < 4; nf++)
        #pragma unroll
        for (int r = 0; r < 4; r++){
          float pv = __expf(sacc[mf][nf][r]);
          sacc[mf][nf][r] = pv;
          lpart[mf][r] += pv;
        }

    // write P (bf16, conflict-free swizzle)
    #pragma unroll
    for (int mf = 0; mf < 2; mf++)
      #pragma unroll
      for (int nf = 0; nf < 4; nf++)
        #pragma unroll
        for (int r = 0; r < 4; r++){
          int q = w * 32 + mf * 16 + g * 4 + r;
          int key = nf * 16 + c;
          *(unsigned short*)(PsB + q * 128 + ((key * 2) ^ (((q >> 2) & 3) << 5))) = f2bf(sacc[mf][nf][r]);
        }
    __syncthreads();   // P visible; next-tile loads drained (they flew under QK^T+exp)

    // O += P V  (wave: 32 q-rows x 128 d)
    __builtin_amdgcn_s_setprio(1);
    #pragma unroll
    for (int kk = 0; kk < 2; kk++){
      bf16x8 pa[2], vv[8];
      #pragma unroll
      for (int mf = 0; mf < 2; mf++){
        int q = w * 32 + mf * 16 + c;
        pa[mf] = *(const bf16x8*)(PsB + q * 128 + ((kk * 64 + g * 16) ^ (((q >> 2) & 3) << 5)));
      }
      #pragma unroll
      for (int df = 0; df < 8; df++){
        int d = df * 16 + c;
        vv[df] = *(const bf16x8*)(Vc + d * 128 + ((kk * 64 + g * 16) ^ ((d & 7) << 4)));
      }
      #pragma unroll
      for (int mf = 0; mf < 2; mf++)
        #pragma unroll
        for (int df = 0; df < 8; df++)
          oacc[mf][df] = __builtin_amdgcn_mfma_f32_16x16x32_bf16(pa[mf], vv[df], oacc[mf][df], 0, 0, 0);
    }
    __builtin_amdgcn_s_setprio(0);
    __syncthreads();   // all reads of K[cur]/V[cur]/Ps done before reuse
  }

  // epilogue: single cross-lane l-reduction, normalize, write (B,N,D) bf16
  int b = bh >> 4, h = bh & 15;
  #pragma unroll
  for (int mf = 0; mf < 2; mf++)
    #pragma unroll
    for (int r = 0; r < 4; r++){
      float s = lpart[mf][r];
      #pragma unroll
      for (int off = 1; off < 16; off <<= 1) s += __shfl_xor(s, off);
      float inv = 1.f / s;
      int qg = qt * 128 + w * 32 + mf * 16 + g * 4 + r;
      size_t rowbase = ((size_t)(b * 2048 + qg)) * 2048 + h * 128;
      #pragma unroll
      for (int df = 0; df < 8; df++)
        Ao[rowbase + df * 16 + c] = f2bf(oacc[mf][df][r] * inv);
    }
}

extern "C" void kernel_launch(void* const* d_in, const int* in_sizes, int n_in,
                              void* d_out, int out_size, void* d_ws, size_t ws_size,
                              hipStream_t stream){
  const float* x      = (const float*)d_in[0];
  const float* q_rope = (const float*)d_in[1];
  const float* k_rope = (const float*)d_in[2];
  const float* Wq     = (const float*)d_in[3];
  const float* Wk     = (const float*)d_in[4];
  const float* Wv     = (const float*)d_in[5];
  const float* Wo     = (const float*)d_in[6];
  const float* bo     = (const float*)d_in[7];
  char* ws = (char*)d_ws;
  unsigned short* xb  = (unsigned short*)(ws);
  unsigned short* wqT = (unsigned short*)(ws + 16777216);
  unsigned short* woT = (unsigned short*)(ws + 41943040);
  unsigned short* qb  = (unsigned short*)(ws + 50331648);
  unsigned short* kbf = (unsigned short*)(ws + 67108864);
  unsigned short* vt  = (unsigned short*)(ws + 83886080);
  unsigned short* ab  = (unsigned short*)(ws + 100663296);

  k_cvt<<<8192, 256, 0, stream>>>(x, xb, 2097152);
  dim3 tg(32, 32, 4);
  k_transpose_all<<<tg, 256, 0, stream>>>(Wq, Wk, Wv, Wo, wqT);
  dim3 gq(32, 48);
  k_gemm_qkv<<<gq, 256, 0, stream>>>(xb, wqT, qb, kbf, vt, q_rope, k_rope);
  dim3 ga(16, 32);
  k_attn<<<ga, 256, 0, stream>>>(qb, kbf, vt, ab);
  dim3 go(32, 16);
  k_gemm_out<<<go, 256, 0, stream>>>(ab, woT, (float*)d_out, bo);
}

// Round 5
// 266.845 us; speedup vs baseline: 1.0486x; 1.0486x over previous
//
#include <hip/hip_runtime.h>
#include <hip/hip_bf16.h>
#include <stdint.h>

// Shapes: B=2, N=2048, D=2048, H=16, Dh=128, M=B*N=4096
// Workspace layout (bytes):
//   xb   @ 0          bf16 x (4096x2048)
//   wqT  @ 16777216   bf16 Wq^T (2048,2048)   } contiguous => W_qkv^T (6144,2048)
//   wkT  @ 25165824
//   wvT  @ 33554432
//   woT  @ 41943040
//   qb   @ 50331648   bf16 Q (B,H,N,Dh)  (rope+scale applied)
//   kb   @ 67108864   bf16 K (B,H,N,Dh)  (rope applied)
//   vt   @ 83886080   bf16 V^T (B,H,Dh,N)
//   ab   @ 100663296  bf16 attn_out (B,N,D)

typedef __attribute__((ext_vector_type(4))) float f32x4;
typedef __attribute__((ext_vector_type(8))) short bf16x8;

__device__ __forceinline__ unsigned short f2bf(float f){
  unsigned u = __builtin_bit_cast(unsigned, f);
  u += 0x7FFFu + ((u >> 16) & 1u);
  return (unsigned short)(u >> 16);
}
__device__ __forceinline__ float bf2f(unsigned short h){
  unsigned u = ((unsigned)h) << 16;
  return __builtin_bit_cast(float, u);
}
__device__ __forceinline__ void gload16(const void* g, void* l){
  __builtin_amdgcn_global_load_lds((const __attribute__((address_space(1))) void*)g,
                                   (__attribute__((address_space(3))) void*)l, 16, 0, 0);
}

// ---------------- elementwise f32 -> bf16 ----------------
__global__ void k_cvt(const float* __restrict__ src, unsigned short* __restrict__ dst, int n4){
  int i = blockIdx.x * 256 + threadIdx.x;
  if (i >= n4) return;
  float4 v = ((const float4*)src)[i];
  unsigned long long pk = (unsigned long long)f2bf(v.x)
    | ((unsigned long long)f2bf(v.y) << 16)
    | ((unsigned long long)f2bf(v.z) << 32)
    | ((unsigned long long)f2bf(v.w) << 48);
  ((unsigned long long*)dst)[i] = pk;
}

// ---------------- all four W (K,N) f32 -> W^T (N,K) bf16, one launch ----------------
__global__ void k_transpose_all(const float* __restrict__ W0, const float* __restrict__ W1,
                                const float* __restrict__ W2, const float* __restrict__ W3,
                                unsigned short* __restrict__ WT){
  const float* W = (blockIdx.z == 0) ? W0 : (blockIdx.z == 1) ? W1 : (blockIdx.z == 2) ? W2 : W3;
  unsigned short* dst = WT + (size_t)blockIdx.z * 4194304;
  __shared__ float tile[64][65];
  int t = threadIdx.x;
  int cc = t & 63, rb = t >> 6;
  int bx = blockIdx.x * 64;   // n base
  int by = blockIdx.y * 64;   // k base
  #pragma unroll
  for (int i = 0; i < 16; i++){
    int r = rb + i * 4;
    tile[r][cc] = W[(size_t)(by + r) * 2048 + bx + cc];
  }
  __syncthreads();
  #pragma unroll
  for (int i = 0; i < 16; i++){
    int r = rb + i * 4;
    dst[(size_t)(bx + r) * 2048 + by + cc] = f2bf(tile[cc][r]);
  }
}

// ---------------- fused QKV GEMM + RoPE epilogue ----------------
// m-band XCD swizzle: XCD j owns m-tiles [4j,4j+4) x ALL n-tiles -> its A
// working set (4*128 rows * 4KB = 2MB) stays L2-resident for the whole
// kernel; B streams via L3 once. (Round-3's n-band variant thrashed A.)
__global__ __launch_bounds__(256, 3) void k_gemm_qkv(
    const unsigned short* __restrict__ A,
    const unsigned short* __restrict__ Bt,
    unsigned short* __restrict__ Oq,
    unsigned short* __restrict__ Ok,
    unsigned short* __restrict__ Ov,
    const float* __restrict__ ropeq,
    const float* __restrict__ ropek)
{
  const int Kdim = 2048;
  __shared__ unsigned short As[128 * 64];
  __shared__ unsigned short Bs[128 * 64];
  const int tid = threadIdx.x;
  const int w = tid >> 6, l = tid & 63, g = l >> 4, c = l & 15;
  const int i0 = blockIdx.y * 32 + blockIdx.x;   // 0..1535
  const int xcd = i0 & 7, r0 = i0 >> 3;          // r0 0..191
  const int bm = (xcd * 4 + (r0 & 3)) * 128;     // m-band per XCD
  const int bn = (r0 >> 2) * 128;                // n advances slowly
  const int mw = (w >> 1) * 64, nw = (w & 1) * 64;
  f32x4 acc[4][4] = {};
  const int srow = l >> 3;
  const int sbyte = (((l & 7) ^ srow) << 4);
  const char* Ab = (const char*)A;
  const char* Bb = (const char*)Bt;
  char* AsB = (char*)As; char* BsB = (char*)Bs;

  for (int kt = 0; kt < Kdim; kt += 64){
    __syncthreads();
    #pragma unroll
    for (int j = 0; j < 4; j++){
      int chunk = w * 4 + j;
      int row = chunk * 8 + srow;
      gload16(Ab + ((size_t)(bm + row) * Kdim + kt) * 2 + sbyte, AsB + chunk * 1024);
      gload16(Bb + ((size_t)(bn + row) * Kdim + kt) * 2 + sbyte, BsB + chunk * 1024);
    }
    __syncthreads();
    #pragma unroll
    for (int kk = 0; kk < 2; kk++){
      bf16x8 av[4], bv[4];
      #pragma unroll
      for (int i = 0; i < 4; i++){
        int m = mw + i * 16 + c;
        av[i] = *(const bf16x8*)(AsB + m * 128 + ((kk * 64 + g * 16) ^ ((m & 7) << 4)));
        int n = nw + i * 16 + c;
        bv[i] = *(const bf16x8*)(BsB + n * 128 + ((kk * 64 + g * 16) ^ ((n & 7) << 4)));
      }
      #pragma unroll
      for (int i = 0; i < 4; i++)
        #pragma unroll
        for (int jj = 0; jj < 4; jj++)
          acc[i][jj] = __builtin_amdgcn_mfma_f32_16x16x32_bf16(av[i], bv[jj], acc[i][jj], 0, 0, 0);
    }
  }

  const int matsel = bn >> 11;        // 0=Q 1=K 2=V
  const int hh = (bn >> 7) & 15;      // head
  if (matsel < 2){
    unsigned short* O = matsel ? Ok : Oq;
    const float* rope = matsel ? ropek : ropeq;
    const float scale = matsel ? 1.0f : (1.0f / 128.0f);
    #pragma unroll
    for (int i = 0; i < 4; i++){
      int m0 = bm + mw + i * 16 + g * 4;
      #pragma unroll
      for (int jj = 0; jj < 4; jj++){
        int d = nw + jj * 16 + c;   // 0..127 within head
        int dbase = d & ~1;
        int odd = d & 1;
        #pragma unroll
        for (int r = 0; r < 4; r++){
          int m = m0 + r;
          int b = m >> 11, tok = m & 2047;
          float v = acc[i][jj][r];
          float vp = __shfl_xor(v, 1);
          float2 rv = *(const float2*)(rope + (((size_t)(b * 2048 + tok)) << 7) + dbase);
          float xr = odd ? vp : v;
          float xi = odd ? v : vp;
          float res = odd ? (xr * rv.y + xi * rv.x) : (xr * rv.x - xi * rv.y);
          O[(((size_t)(b * 16 + hh) * 2048 + tok) << 7) + d] = f2bf(res * scale);
        }
      }
    }
  } else { // V -> (B,H,Dh,N)
    #pragma unroll
    for (int i = 0; i < 4; i++){
      int m0 = bm + mw + i * 16 + g * 4;
      int b = m0 >> 11, tok0 = m0 & 2047;
      #pragma unroll
      for (int jj = 0; jj < 4; jj++){
        int d = nw + jj * 16 + c;
        unsigned long long pk = (unsigned long long)f2bf(acc[i][jj][0])
          | ((unsigned long long)f2bf(acc[i][jj][1]) << 16)
          | ((unsigned long long)f2bf(acc[i][jj][2]) << 32)
          | ((unsigned long long)f2bf(acc[i][jj][3]) << 48);
        *(unsigned long long*)(Ov + ((size_t)(b * 16 + hh) * 128 + d) * 2048 + tok0) = pk;
      }
    }
  }
}

// ---------------- output GEMM: d_out = ab @ Wo + bo (f32 out) ----------------
__global__ __launch_bounds__(256, 3) void k_gemm_out(
    const unsigned short* __restrict__ A,
    const unsigned short* __restrict__ Bt,
    float* __restrict__ O,
    const float* __restrict__ bias)
{
  const int Kdim = 2048;
  __shared__ unsigned short As[128 * 64];
  __shared__ unsigned short Bs[128 * 64];
  const int tid = threadIdx.x;
  const int w = tid >> 6, l = tid & 63, g = l >> 4, c = l & 15;
  const int i0 = blockIdx.y * 32 + blockIdx.x;   // 0..511
  const int xcd = i0 & 7, r0 = i0 >> 3;          // r0 0..63
  const int bm = (xcd * 4 + (r0 & 3)) * 128;     // m-band per XCD
  const int bn = (r0 >> 2) * 128;                // 0..15
  const int mw = (w >> 1) * 64, nw = (w & 1) * 64;
  f32x4 acc[4][4] = {};
  const int srow = l >> 3;
  const int sbyte = (((l & 7) ^ srow) << 4);
  const char* Ab = (const char*)A;
  const char* Bb = (const char*)Bt;
  char* AsB = (char*)As; char* BsB = (char*)Bs;

  for (int kt = 0; kt < Kdim; kt += 64){
    __syncthreads();
    #pragma unroll
    for (int j = 0; j < 4; j++){
      int chunk = w * 4 + j;
      int row = chunk * 8 + srow;
      gload16(Ab + ((size_t)(bm + row) * Kdim + kt) * 2 + sbyte, AsB + chunk * 1024);
      gload16(Bb + ((size_t)(bn + row) * Kdim + kt) * 2 + sbyte, BsB + chunk * 1024);
    }
    __syncthreads();
    #pragma unroll
    for (int kk = 0; kk < 2; kk++){
      bf16x8 av[4], bv[4];
      #pragma unroll
      for (int i = 0; i < 4; i++){
        int m = mw + i * 16 + c;
        av[i] = *(const bf16x8*)(AsB + m * 128 + ((kk * 64 + g * 16) ^ ((m & 7) << 4)));
        int n = nw + i * 16 + c;
        bv[i] = *(const bf16x8*)(BsB + n * 128 + ((kk * 64 + g * 16) ^ ((n & 7) << 4)));
      }
      #pragma unroll
      for (int i = 0; i < 4; i++)
        #pragma unroll
        for (int jj = 0; jj < 4; jj++)
          acc[i][jj] = __builtin_amdgcn_mfma_f32_16x16x32_bf16(av[i], bv[jj], acc[i][jj], 0, 0, 0);
    }
  }
  #pragma unroll
  for (int i = 0; i < 4; i++){
    int m0 = bm + mw + i * 16 + g * 4;
    #pragma unroll
    for (int jj = 0; jj < 4; jj++){
      int n = bn + nw + jj * 16 + c;
      float bv2 = bias[n];
      #pragma unroll
      for (int r = 0; r < 4; r++)
        O[(size_t)(m0 + r) * 2048 + n] = acc[i][jj][r] + bv2;
    }
  }
}

// ---------------- Flash attention ----------------
// Q in regs, K/V double-buffered, fixed-base softmax (|S|<~1 here), deferred
// l-reduction, conflict-free P swizzle, head-band XCD swizzle (4 heads' K+V
// = 4MB per XCD L2), setprio around MFMA clusters.
__global__ __launch_bounds__(256, 2) void k_attn(
    const unsigned short* __restrict__ Q,
    const unsigned short* __restrict__ Kg,
    const unsigned short* __restrict__ VT,
    unsigned short* __restrict__ Ao)
{
  __shared__ char sh[81920];
  // layout: K0 @0 (16KB) | K1 @16KB | V0 @32KB | V1 @48KB | Ps @64KB (16KB)
  char* PsB = sh + 65536;
  const int tid = threadIdx.x;
  const int w = tid >> 6, l = tid & 63, g = l >> 4, c = l & 15;
  // 512 blocks: XCD j gets heads [4j, 4j+4), all 16 q-tiles
  const int i0 = blockIdx.y * 16 + blockIdx.x;
  const int xcd = i0 & 7, kb2 = i0 >> 3;
  const int bh = xcd * 4 + (kb2 >> 4);
  const int qt = kb2 & 15;
  const char* Qb = (const char*)(Q + (((size_t)bh * 2048 + qt * 128) << 7));
  const char* Kb = (const char*)(Kg + ((size_t)bh << 18));
  const char* Vb = (const char*)(VT + ((size_t)bh << 18));
  const int rsub = l >> 4;
  const int byte0 = (l & 15) << 4;
  const int drow = l >> 3;
  const int vbyte = (((l & 7) ^ drow) << 4);

  // stage Q tile (32KB) through K0|K1 region, then hoist frags to regs
  #pragma unroll
  for (int j = 0; j < 8; j++){
    int chunk = w * 8 + j;
    int row = chunk * 4 + rsub;
    gload16(Qb + (size_t)row * 256 + (byte0 ^ ((row & 7) << 4)), sh + chunk * 1024);
  }
  __syncthreads();
  bf16x8 qa[4][2];
  #pragma unroll
  for (int kk = 0; kk < 4; kk++)
    #pragma unroll
    for (int mf = 0; mf < 2; mf++){
      int q = w * 32 + mf * 16 + c;
      qa[kk][mf] = *(const bf16x8*)(sh + q * 256 + ((kk * 64 + g * 16) ^ ((q & 7) << 4)));
    }
  __syncthreads();   // frag reads done before staging overwrites

  auto stageKV = [&](int kv, int buf){
    char* Kc = sh + buf * 16384;
    char* Vc = sh + 32768 + buf * 16384;
    #pragma unroll
    for (int j = 0; j < 4; j++){
      int chunk = w * 4 + j;
      int row = chunk * 4 + rsub;
      gload16(Kb + (size_t)(kv * 64 + row) * 256 + (byte0 ^ ((row & 7) << 4)), Kc + chunk * 1024);
    }
    #pragma unroll
    for (int j = 0; j < 4; j++){
      int chunk = w * 4 + j;
      int d = chunk * 8 + drow;
      gload16(Vb + (size_t)d * 4096 + kv * 128 + vbyte, Vc + chunk * 1024);
    }
  };

  f32x4 oacc[2][8] = {};
  float lpart[2][4] = {};

  stageKV(0, 0);
  __syncthreads();

  for (int kv = 0; kv < 32; kv++){
    int cur = kv & 1;
    if (kv < 31) stageKV(kv + 1, cur ^ 1);   // flies under QK^T + exp
    char* Kc = sh + cur * 16384;
    char* Vc = sh + 32768 + cur * 16384;

    // S = Q K^T  (wave: 32 q-rows x 64 keys)
    f32x4 sacc[2][4] = {};
    __builtin_amdgcn_s_setprio(1);
    #pragma unroll
    for (int kk = 0; kk < 4; kk++){
      bf16x8 kbf[4];
      #pragma unroll
      for (int nf = 0; nf < 4; nf++){
        int kx = nf * 16 + c;
        kbf[nf] = *(const bf16x8*)(Kc + kx * 256 + ((kk * 64 + g * 16) ^ ((kx & 7) << 4)));
      }
      #pragma unroll
      for (int mf = 0; mf < 2; mf++)
        #pragma unroll
        for (int nf = 0; nf < 4; nf++)
          sacc[mf][nf] = __builtin_amdgcn_mfma_f32_16x16x32_bf16(qa[kk][mf], kbf[nf], sacc[mf][nf], 0, 0, 0);
    }
    __builtin_amdgcn_s_setprio(0);

    // fixed-base softmax numerator: P = exp(S), per-lane partial row sums.
    #pragma unroll
    for (int mf = 0; mf < 2; mf++)
      #pragma unroll
      for (int nf = 0; nf < 4; nf++)
        #pragma unroll
        for (int r = 0; r < 4; r++){
          float pv = __expf(sacc[mf][nf][r]);
          sacc[mf][nf][r] = pv;
          lpart[mf][r] += pv;
        }

    // write P (bf16, conflict-free swizzle)
    #pragma unroll
    for (int mf = 0; mf < 2; mf++)
      #pragma unroll
      for (int nf = 0; nf < 4; nf++)
        #pragma unroll
        for (int r = 0; r < 4; r++){
          int q = w * 32 + mf * 16 + g * 4 + r;
          int key = nf * 16 + c;
          *(unsigned short*)(PsB + q * 128 + ((key * 2) ^ (((q >> 2) & 3) << 5))) = f2bf(sacc[mf][nf][r]);
        }
    __syncthreads();   // P visible; next-tile loads drained (they flew under QK^T+exp)

    // O += P V  (wave: 32 q-rows x 128 d)
    __builtin_amdgcn_s_setprio(1);
    #pragma unroll
    for (int kk = 0; kk < 2; kk++){
      bf16x8 pa[2], vv[8];
      #pragma unroll
      for (int mf = 0; mf < 2; mf++){
        int q = w * 32 + mf * 16 + c;
        pa[mf] = *(const bf16x8*)(PsB + q * 128 + ((kk * 64 + g * 16) ^ (((q >> 2) & 3) << 5)));
      }
      #pragma unroll
      for (int df = 0; df < 8; df++){
        int d = df * 16 + c;
        vv[df] = *(const bf16x8*)(Vc + d * 128 + ((kk * 64 + g * 16) ^ ((d & 7) << 4)));
      }
      #pragma unroll
      for (int mf = 0; mf < 2; mf++)
        #pragma unroll
        for (int df = 0; df < 8; df++)
          oacc[mf][df] = __builtin_amdgcn_mfma_f32_16x16x32_bf16(pa[mf], vv[df], oacc[mf][df], 0, 0, 0);
    }
    __builtin_amdgcn_s_setprio(0);
    __syncthreads();   // all reads of K[cur]/V[cur]/Ps done before reuse
  }

  // epilogue: single cross-lane l-reduction, normalize, write (B,N,D) bf16
  int b = bh >> 4, h = bh & 15;
  #pragma unroll
  for (int mf = 0; mf < 2; mf++)
    #pragma unroll
    for (int r = 0; r < 4; r++){
      float s = lpart[mf][r];
      #pragma unroll
      for (int off = 1; off < 16; off <<= 1) s += __shfl_xor(s, off);
      float inv = 1.f / s;
      int qg = qt * 128 + w * 32 + mf * 16 + g * 4 + r;
      size_t rowbase = ((size_t)(b * 2048 + qg)) * 2048 + h * 128;
      #pragma unroll
      for (int df = 0; df < 8; df++)
        Ao[rowbase + df * 16 + c] = f2bf(oacc[mf][df][r] * inv);
    }
}

extern "C" void kernel_launch(void* const* d_in, const int* in_sizes, int n_in,
                              void* d_out, int out_size, void* d_ws, size_t ws_size,
                              hipStream_t stream){
  const float* x      = (const float*)d_in[0];
  const float* q_rope = (const float*)d_in[1];
  const float* k_rope = (const float*)d_in[2];
  const float* Wq     = (const float*)d_in[3];
  const float* Wk     = (const float*)d_in[4];
  const float* Wv     = (const float*)d_in[5];
  const float* Wo     = (const float*)d_in[6];
  const float* bo     = (const float*)d_in[7];
  char* ws = (char*)d_ws;
  unsigned short* xb  = (unsigned short*)(ws);
  unsigned short* wqT = (unsigned short*)(ws + 16777216);
  unsigned short* woT = (unsigned short*)(ws + 41943040);
  unsigned short* qb  = (unsigned short*)(ws + 50331648);
  unsigned short* kbf = (unsigned short*)(ws + 67108864);
  unsigned short* vt  = (unsigned short*)(ws + 83886080);
  unsigned short* ab  = (unsigned short*)(ws + 100663296);

  k_cvt<<<8192, 256, 0, stream>>>(x, xb, 2097152);
  dim3 tg(32, 32, 4);
  k_transpose_all<<<tg, 256, 0, stream>>>(Wq, Wk, Wv, Wo, wqT);
  dim3 gq(32, 48);
  k_gemm_qkv<<<gq, 256, 0, stream>>>(xb, wqT, qb, kbf, vt, q_rope, k_rope);
  dim3 ga(16, 32);
  k_attn<<<ga, 256, 0, stream>>>(qb, kbf, vt, ab);
  dim3 go(32, 16);
  k_gemm_out<<<go, 256, 0, stream>>>(ab, woT, (float*)d_out, bo);
}

// Round 7
// 255.898 us; speedup vs baseline: 1.0934x; 1.0428x over previous
//
#include <hip/hip_runtime.h>
#include <hip/hip_bf16.h>
#include <stdint.h>

// Shapes: B=2, N=2048, D=2048, H=16, Dh=128, M=B*N=4096
// Workspace layout (bytes):
//   xb   @ 0          bf16 x (4096x2048)
//   wqT  @ 16777216   bf16 Wq^T (2048,2048)   } contiguous => W_qkv^T (6144,2048)
//   wkT  @ 25165824
//   wvT  @ 33554432
//   woT  @ 41943040
//   qb   @ 50331648   bf16 Q (B,H,N,Dh)  (rope+scale applied)
//   kb   @ 67108864   bf16 K (B,H,N,Dh)  (rope applied)
//   vt   @ 83886080   bf16 V^T (B,H,Dh,N)
//   ab   @ 100663296  bf16 attn_out (B,N,D)

typedef __attribute__((ext_vector_type(4))) float f32x4;
typedef __attribute__((ext_vector_type(8))) short bf16x8;

__device__ __forceinline__ unsigned short f2bf(float f){
  unsigned u = __builtin_bit_cast(unsigned, f);
  u += 0x7FFFu + ((u >> 16) & 1u);
  return (unsigned short)(u >> 16);
}
__device__ __forceinline__ float bf2f(unsigned short h){
  unsigned u = ((unsigned)h) << 16;
  return __builtin_bit_cast(float, u);
}
__device__ __forceinline__ void gload16(const void* g, void* l){
  __builtin_amdgcn_global_load_lds((const __attribute__((address_space(1))) void*)g,
                                   (__attribute__((address_space(3))) void*)l, 16, 0, 0);
}
__device__ __forceinline__ void drain_all(){
  asm volatile("s_waitcnt vmcnt(0) lgkmcnt(0)" ::: "memory");
  __builtin_amdgcn_sched_barrier(0);
}

// ---------------- elementwise f32 -> bf16 ----------------
__global__ void k_cvt(const float* __restrict__ src, unsigned short* __restrict__ dst, int n4){
  int i = blockIdx.x * 256 + threadIdx.x;
  if (i >= n4) return;
  float4 v = ((const float4*)src)[i];
  unsigned long long pk = (unsigned long long)f2bf(v.x)
    | ((unsigned long long)f2bf(v.y) << 16)
    | ((unsigned long long)f2bf(v.z) << 32)
    | ((unsigned long long)f2bf(v.w) << 48);
  ((unsigned long long*)dst)[i] = pk;
}

// ---------------- all four W (K,N) f32 -> W^T (N,K) bf16, one launch ----------------
__global__ void k_transpose_all(const float* __restrict__ W0, const float* __restrict__ W1,
                                const float* __restrict__ W2, const float* __restrict__ W3,
                                unsigned short* __restrict__ WT){
  const float* W = (blockIdx.z == 0) ? W0 : (blockIdx.z == 1) ? W1 : (blockIdx.z == 2) ? W2 : W3;
  unsigned short* dst = WT + (size_t)blockIdx.z * 4194304;
  __shared__ float tile[64][65];
  int t = threadIdx.x;
  int cc = t & 63, rb = t >> 6;
  int bx = blockIdx.x * 64;   // n base
  int by = blockIdx.y * 64;   // k base
  #pragma unroll
  for (int i = 0; i < 16; i++){
    int r = rb + i * 4;
    tile[r][cc] = W[(size_t)(by + r) * 2048 + bx + cc];
  }
  __syncthreads();
  #pragma unroll
  for (int i = 0; i < 16; i++){
    int r = rb + i * 4;
    dst[(size_t)(bx + r) * 2048 + by + cc] = f2bf(tile[cc][r]);
  }
}

// ---------------- fused QKV GEMM + RoPE epilogue ----------------
// 256x128 tile, BK=64, 8 waves (4M x 2N), LDS double-buffered (2 x 48KB),
// ONE barrier per K-step: next-tile global_load_lds issued BEFORE the
// ds_read+MFMA phase, drained (explicitly) at the end-of-iter barrier.
// m-band XCD swizzle: XCD j owns m-tiles {2j,2j+1} (2MB of A, L2-resident).
__global__ __launch_bounds__(512, 2) void k_gemm_qkv(
    const unsigned short* __restrict__ A,
    const unsigned short* __restrict__ Bt,
    unsigned short* __restrict__ Oq,
    unsigned short* __restrict__ Ok,
    unsigned short* __restrict__ Ov,
    const float* __restrict__ ropeq,
    const float* __restrict__ ropek)
{
  const int Kdim = 2048;
  __shared__ char sh[98304];   // 2 x (A 32KB | B 16KB)
  const int tid = threadIdx.x;
  const int w = tid >> 6, l = tid & 63, g = l >> 4, c = l & 15;
  const int i0 = blockIdx.y * 16 + blockIdx.x;   // 0..767
  const int xcd = i0 & 7, r0 = i0 >> 3;          // r0 0..95
  const int bm = (xcd * 2 + (r0 & 1)) * 256;     // m-band per XCD
  const int bn = (r0 >> 1) * 128;                // n advances slowly
  const int mw = (w >> 1) * 64, nw = (w & 1) * 64;
  f32x4 acc[4][4] = {};
  const int srow = l >> 3;
  const int sbyte = (((l & 7) ^ srow) << 4);
  const char* Ab = (const char*)A;
  const char* Bb = (const char*)Bt;

  auto stage = [&](int kt, int buf){
    char* Abuf = sh + buf * 49152;
    char* Bbuf = Abuf + 32768;
    #pragma unroll
    for (int j = 0; j < 4; j++){
      int ch = w * 4 + j;           // 0..31
      int row = ch * 8 + srow;      // 0..255
      gload16(Ab + ((size_t)(bm + row) * Kdim + kt) * 2 + sbyte, Abuf + ch * 1024);
    }
    #pragma unroll
    for (int j = 0; j < 2; j++){
      int ch = w * 2 + j;           // 0..15
      int row = ch * 8 + srow;      // 0..127
      gload16(Bb + ((size_t)(bn + row) * Kdim + kt) * 2 + sbyte, Bbuf + ch * 1024);
    }
  };

  stage(0, 0);
  drain_all();
  __syncthreads();
  for (int t = 0; t < 32; t++){
    int cur = t & 1;
    if (t < 31) stage((t + 1) * 64, cur ^ 1);   // flies under ds_read + MFMA
    char* Abuf = sh + cur * 49152;
    char* Bbuf = Abuf + 32768;
    #pragma unroll
    for (int kk = 0; kk < 2; kk++){
      bf16x8 av[4], bv[4];
      #pragma unroll
      for (int i = 0; i < 4; i++){
        int m = mw + i * 16 + c;
        av[i] = *(const bf16x8*)(Abuf + m * 128 + ((kk * 64 + g * 16) ^ ((m & 7) << 4)));
        int n = nw + i * 16 + c;
        bv[i] = *(const bf16x8*)(Bbuf + n * 128 + ((kk * 64 + g * 16) ^ ((n & 7) << 4)));
      }
      #pragma unroll
      for (int i = 0; i < 4; i++)
        #pragma unroll
        for (int jj = 0; jj < 4; jj++)
          acc[i][jj] = __builtin_amdgcn_mfma_f32_16x16x32_bf16(av[i], bv[jj], acc[i][jj], 0, 0, 0);
    }
    drain_all();       // staged loads for cur^1 landed; buf[cur] reads done
    __syncthreads();
  }

  const int matsel = bn >> 11;        // 0=Q 1=K 2=V
  const int hh = (bn >> 7) & 15;      // head
  if (matsel < 2){
    unsigned short* O = matsel ? Ok : Oq;
    const float* rope = matsel ? ropek : ropeq;
    const float scale = matsel ? 1.0f : (1.0f / 128.0f);
    #pragma unroll
    for (int i = 0; i < 4; i++){
      int m0 = bm + mw + i * 16 + g * 4;
      #pragma unroll
      for (int jj = 0; jj < 4; jj++){
        int d = nw + jj * 16 + c;   // 0..127 within head
        int dbase = d & ~1;
        int odd = d & 1;
        #pragma unroll
        for (int r = 0; r < 4; r++){
          int m = m0 + r;
          int b = m >> 11, tok = m & 2047;
          float v = acc[i][jj][r];
          float vp = __shfl_xor(v, 1);
          float2 rv = *(const float2*)(rope + (((size_t)(b * 2048 + tok)) << 7) + dbase);
          float xr = odd ? vp : v;
          float xi = odd ? v : vp;
          float res = odd ? (xr * rv.y + xi * rv.x) : (xr * rv.x - xi * rv.y);
          O[(((size_t)(b * 16 + hh) * 2048 + tok) << 7) + d] = f2bf(res * scale);
        }
      }
    }
  } else { // V -> (B,H,Dh,N)
    #pragma unroll
    for (int i = 0; i < 4; i++){
      int m0 = bm + mw + i * 16 + g * 4;
      int b = m0 >> 11, tok0 = m0 & 2047;
      #pragma unroll
      for (int jj = 0; jj < 4; jj++){
        int d = nw + jj * 16 + c;
        unsigned long long pk = (unsigned long long)f2bf(acc[i][jj][0])
          | ((unsigned long long)f2bf(acc[i][jj][1]) << 16)
          | ((unsigned long long)f2bf(acc[i][jj][2]) << 32)
          | ((unsigned long long)f2bf(acc[i][jj][3]) << 48);
        *(unsigned long long*)(Ov + ((size_t)(b * 16 + hh) * 128 + d) * 2048 + tok0) = pk;
      }
    }
  }
}

// ---------------- output GEMM: d_out = ab @ Wo + bo (f32 out) ----------------
// Same 256x128 1-barrier dbuf structure; 256 blocks = exactly 1 full round.
__global__ __launch_bounds__(512, 2) void k_gemm_out(
    const unsigned short* __restrict__ A,
    const unsigned short* __restrict__ Bt,
    float* __restrict__ O,
    const float* __restrict__ bias)
{
  const int Kdim = 2048;
  __shared__ char sh[98304];
  const int tid = threadIdx.x;
  const int w = tid >> 6, l = tid & 63, g = l >> 4, c = l & 15;
  const int i0 = blockIdx.y * 16 + blockIdx.x;   // 0..255
  const int xcd = i0 & 7, r0 = i0 >> 3;          // r0 0..31
  const int bm = (xcd * 2 + (r0 & 1)) * 256;
  const int bn = (r0 >> 1) * 128;                // 0..15 tiles
  const int mw = (w >> 1) * 64, nw = (w & 1) * 64;
  f32x4 acc[4][4] = {};
  const int srow = l >> 3;
  const int sbyte = (((l & 7) ^ srow) << 4);
  const char* Ab = (const char*)A;
  const char* Bb = (const char*)Bt;

  auto stage = [&](int kt, int buf){
    char* Abuf = sh + buf * 49152;
    char* Bbuf = Abuf + 32768;
    #pragma unroll
    for (int j = 0; j < 4; j++){
      int ch = w * 4 + j;
      int row = ch * 8 + srow;
      gload16(Ab + ((size_t)(bm + row) * Kdim + kt) * 2 + sbyte, Abuf + ch * 1024);
    }
    #pragma unroll
    for (int j = 0; j < 2; j++){
      int ch = w * 2 + j;
      int row = ch * 8 + srow;
      gload16(Bb + ((size_t)(bn + row) * Kdim + kt) * 2 + sbyte, Bbuf + ch * 1024);
    }
  };

  stage(0, 0);
  drain_all();
  __syncthreads();
  for (int t = 0; t < 32; t++){
    int cur = t & 1;
    if (t < 31) stage((t + 1) * 64, cur ^ 1);
    char* Abuf = sh + cur * 49152;
    char* Bbuf = Abuf + 32768;
    #pragma unroll
    for (int kk = 0; kk < 2; kk++){
      bf16x8 av[4], bv[4];
      #pragma unroll
      for (int i = 0; i < 4; i++){
        int m = mw + i * 16 + c;
        av[i] = *(const bf16x8*)(Abuf + m * 128 + ((kk * 64 + g * 16) ^ ((m & 7) << 4)));
        int n = nw + i * 16 + c;
        bv[i] = *(const bf16x8*)(Bbuf + n * 128 + ((kk * 64 + g * 16) ^ ((n & 7) << 4)));
      }
      #pragma unroll
      for (int i = 0; i < 4; i++)
        #pragma unroll
        for (int jj = 0; jj < 4; jj++)
          acc[i][jj] = __builtin_amdgcn_mfma_f32_16x16x32_bf16(av[i], bv[jj], acc[i][jj], 0, 0, 0);
    }
    drain_all();
    __syncthreads();
  }
  #pragma unroll
  for (int i = 0; i < 4; i++){
    int m0 = bm + mw + i * 16 + g * 4;
    #pragma unroll
    for (int jj = 0; jj < 4; jj++){
      int n = bn + nw + jj * 16 + c;
      float bv2 = bias[n];
      #pragma unroll
      for (int r = 0; r < 4; r++)
        O[(size_t)(m0 + r) * 2048 + n] = acc[i][jj][r] + bv2;
    }
  }
}

// ---------------- Flash attention ----------------
// Q in regs, K/V double-buffered, fixed-base softmax (|S|<~1 here), deferred
// l-reduction, conflict-free P swizzle, head-band XCD swizzle, setprio.
// P tile is WAVE-PRIVATE; the P-write -> PV-read RAW is ordered by an
// explicit wave-local s_waitcnt lgkmcnt(0) + sched_barrier (the round-6
// removal of the mid __syncthreads also removed the only lgkm wait -> race).
__global__ __launch_bounds__(256, 2) void k_attn(
    const unsigned short* __restrict__ Q,
    const unsigned short* __restrict__ Kg,
    const unsigned short* __restrict__ VT,
    unsigned short* __restrict__ Ao)
{
  __shared__ char sh[81920];
  // layout: K0 @0 (16KB) | K1 @16KB | V0 @32KB | V1 @48KB | Ps @64KB (16KB)
  char* PsB = sh + 65536;
  const int tid = threadIdx.x;
  const int w = tid >> 6, l = tid & 63, g = l >> 4, c = l & 15;
  // 512 blocks: XCD j gets heads [4j, 4j+4), all 16 q-tiles
  const int i0 = blockIdx.y * 16 + blockIdx.x;
  const int xcd = i0 & 7, kb2 = i0 >> 3;
  const int bh = xcd * 4 + (kb2 >> 4);
  const int qt = kb2 & 15;
  const char* Qb = (const char*)(Q + (((size_t)bh * 2048 + qt * 128) << 7));
  const char* Kb = (const char*)(Kg + ((size_t)bh << 18));
  const char* Vb = (const char*)(VT + ((size_t)bh << 18));
  const int rsub = l >> 4;
  const int byte0 = (l & 15) << 4;
  const int drow = l >> 3;
  const int vbyte = (((l & 7) ^ drow) << 4);

  // stage Q tile (32KB) through K0|K1 region, then hoist frags to regs
  #pragma unroll
  for (int j = 0; j < 8; j++){
    int chunk = w * 8 + j;
    int row = chunk * 4 + rsub;
    gload16(Qb + (size_t)row * 256 + (byte0 ^ ((row & 7) << 4)), sh + chunk * 1024);
  }
  __syncthreads();
  bf16x8 qa[4][2];
  #pragma unroll
  for (int kk = 0; kk < 4; kk++)
    #pragma unroll
    for (int mf = 0; mf < 2; mf++){
      int q = w * 32 + mf * 16 + c;
      qa[kk][mf] = *(const bf16x8*)(sh + q * 256 + ((kk * 64 + g * 16) ^ ((q & 7) << 4)));
    }
  __syncthreads();   // frag reads done before staging overwrites

  auto stageKV = [&](int kv, int buf){
    char* Kc = sh + buf * 16384;
    char* Vc = sh + 32768 + buf * 16384;
    #pragma unroll
    for (int j = 0; j < 4; j++){
      int chunk = w * 4 + j;
      int row = chunk * 4 + rsub;
      gload16(Kb + (size_t)(kv * 64 + row) * 256 + (byte0 ^ ((row & 7) << 4)), Kc + chunk * 1024);
    }
    #pragma unroll
    for (int j = 0; j < 4; j++){
      int chunk = w * 4 + j;
      int d = chunk * 8 + drow;
      gload16(Vb + (size_t)d * 4096 + kv * 128 + vbyte, Vc + chunk * 1024);
    }
  };

  f32x4 oacc[2][8] = {};
  float lpart[2][4] = {};

  stageKV(0, 0);
  __syncthreads();

  for (int kv = 0; kv < 32; kv++){
    int cur = kv & 1;
    if (kv < 31) stageKV(kv + 1, cur ^ 1);   // flies under the whole iteration
    char* Kc = sh + cur * 16384;
    char* Vc = sh + 32768 + cur * 16384;

    // S = Q K^T  (wave: 32 q-rows x 64 keys)
    f32x4 sacc[2][4] = {};
    __builtin_amdgcn_s_setprio(1);
    #pragma unroll
    for (int kk = 0; kk < 4; kk++){
      bf16x8 kbf[4];
      #pragma unroll
      for (int nf = 0; nf < 4; nf++){
        int kx = nf * 16 + c;
        kbf[nf] = *(const bf16x8*)(Kc + kx * 256 + ((kk * 64 + g * 16) ^ ((kx & 7) << 4)));
      }
      #pragma unroll
      for (int mf = 0; mf < 2; mf++)
        #pragma unroll
        for (int nf = 0; nf < 4; nf++)
          sacc[mf][nf] = __builtin_amdgcn_mfma_f32_16x16x32_bf16(qa[kk][mf], kbf[nf], sacc[mf][nf], 0, 0, 0);
    }
    __builtin_amdgcn_s_setprio(0);

    // fixed-base softmax numerator: P = exp(S), per-lane partial row sums.
    #pragma unroll
    for (int mf = 0; mf < 2; mf++)
      #pragma unroll
      for (int nf = 0; nf < 4; nf++)
        #pragma unroll
        for (int r = 0; r < 4; r++){
          float pv = __expf(sacc[mf][nf][r]);
          sacc[mf][nf][r] = pv;
          lpart[mf][r] += pv;
        }

    // write P (bf16, conflict-free swizzle) — wave-private rows
    #pragma unroll
    for (int mf = 0; mf < 2; mf++)
      #pragma unroll
      for (int nf = 0; nf < 4; nf++)
        #pragma unroll
        for (int r = 0; r < 4; r++){
          int q = w * 32 + mf * 16 + g * 4 + r;
          int key = nf * 16 + c;
          *(unsigned short*)(PsB + q * 128 + ((key * 2) ^ (((q >> 2) & 3) << 5))) = f2bf(sacc[mf][nf][r]);
        }
    // wave-local RAW fence: P writes must land before PV's ds_read_b128
    asm volatile("s_waitcnt lgkmcnt(0)" ::: "memory");
    __builtin_amdgcn_sched_barrier(0);

    // O += P V  (wave: 32 q-rows x 128 d)
    __builtin_amdgcn_s_setprio(1);
    #pragma unroll
    for (int kk = 0; kk < 2; kk++){
      bf16x8 pa[2], vv[8];
      #pragma unroll
      for (int mf = 0; mf < 2; mf++){
        int q = w * 32 + mf * 16 + c;
        pa[mf] = *(const bf16x8*)(PsB + q * 128 + ((kk * 64 + g * 16) ^ (((q >> 2) & 3) << 5)));
      }
      #pragma unroll
      for (int df = 0; df < 8; df++){
        int d = df * 16 + c;
        vv[df] = *(const bf16x8*)(Vc + d * 128 + ((kk * 64 + g * 16) ^ ((d & 7) << 4)));
      }
      #pragma unroll
      for (int mf = 0; mf < 2; mf++)
        #pragma unroll
        for (int df = 0; df < 8; df++)
          oacc[mf][df] = __builtin_amdgcn_mfma_f32_16x16x32_bf16(pa[mf], vv[df], oacc[mf][df], 0, 0, 0);
    }
    __builtin_amdgcn_s_setprio(0);
    drain_all();       // K/V[cur] reads done; next-tile staging landed
    __syncthreads();
  }

  // epilogue: single cross-lane l-reduction, normalize, write (B,N,D) bf16
  int b = bh >> 4, h = bh & 15;
  #pragma unroll
  for (int mf = 0; mf < 2; mf++)
    #pragma unroll
    for (int r = 0; r < 4; r++){
      float s = lpart[mf][r];
      #pragma unroll
      for (int off = 1; off < 16; off <<= 1) s += __shfl_xor(s, off);
      float inv = 1.f / s;
      int qg = qt * 128 + w * 32 + mf * 16 + g * 4 + r;
      size_t rowbase = ((size_t)(b * 2048 + qg)) * 2048 + h * 128;
      #pragma unroll
      for (int df = 0; df < 8; df++)
        Ao[rowbase + df * 16 + c] = f2bf(oacc[mf][df][r] * inv);
    }
}

extern "C" void kernel_launch(void* const* d_in, const int* in_sizes, int n_in,
                              void* d_out, int out_size, void* d_ws, size_t ws_size,
                              hipStream_t stream){
  const float* x      = (const float*)d_in[0];
  const float* q_rope = (const float*)d_in[1];
  const float* k_rope = (const float*)d_in[2];
  const float* Wq     = (const float*)d_in[3];
  const float* Wk     = (const float*)d_in[4];
  const float* Wv     = (const float*)d_in[5];
  const float* Wo     = (const float*)d_in[6];
  const float* bo     = (const float*)d_in[7];
  char* ws = (char*)d_ws;
  unsigned short* xb  = (unsigned short*)(ws);
  unsigned short* wqT = (unsigned short*)(ws + 16777216);
  unsigned short* woT = (unsigned short*)(ws + 41943040);
  unsigned short* qb  = (unsigned short*)(ws + 50331648);
  unsigned short* kbf = (unsigned short*)(ws + 67108864);
  unsigned short* vt  = (unsigned short*)(ws + 83886080);
  unsigned short* ab  = (unsigned short*)(ws + 100663296);

  k_cvt<<<8192, 256, 0, stream>>>(x, xb, 2097152);
  dim3 tg(32, 32, 4);
  k_transpose_all<<<tg, 256, 0, stream>>>(Wq, Wk, Wv, Wo, wqT);
  dim3 gq(16, 48);
  k_gemm_qkv<<<gq, 512, 0, stream>>>(xb, wqT, qb, kbf, vt, q_rope, k_rope);
  dim3 ga(16, 32);
  k_attn<<<ga, 256, 0, stream>>>(qb, kbf, vt, ab);
  dim3 go(16, 16);
  k_gemm_out<<<go, 512, 0, stream>>>(ab, woT, (float*)d_out, bo);
}